// Round 1
// baseline (243.129 us; speedup 1.0000x reference)
//
#include <hip/hip_runtime.h>
#include <float.h>
#include <math.h>

#define BB 16
#define NN 1024
#define DD 64
#define CC 64
#define KK 20
#define EPSL 1e-3f

// ---------------------------------------------------------------------------
// K1: cterm[u,c] = feats[u,:]·(W1a - W1b)[:,c] + b1[c]
//     nterm[u,c] = feats[u,:]·W1b[:,c]
//     f0c[u]     = feats[u,0]
// One thread per (u,c). w1 is 32 KB, L1/L2-hot; feats row is a broadcast read.
// ---------------------------------------------------------------------------
__global__ void k1_pre(const float* __restrict__ feats, const float* __restrict__ w1,
                       const float* __restrict__ b1, float* __restrict__ cterm,
                       float* __restrict__ nterm, float* __restrict__ f0c) {
    int g = blockIdx.x * blockDim.x + threadIdx.x;   // u*64 + c
    int u = g >> 6;
    int c = g & 63;
    const float* f = feats + (size_t)u * DD;
    float ca = 0.f, nb = 0.f;
#pragma unroll
    for (int d = 0; d < DD; ++d) {
        float fd = f[d];
        ca = fmaf(fd, w1[d * CC + c], ca);            // Σ f_d * W1a[d,c]
        nb = fmaf(fd, w1[(d + DD) * CC + c], nb);     // Σ f_d * W1b[d,c]
    }
    cterm[g] = ca - nb + b1[c];
    nterm[g] = nb;
    if (c == 0) f0c[u] = f[0];
}

// ---------------------------------------------------------------------------
// K2: per row (b,i): indices of the 20 smallest a[j] = adj[row,j]*|f0[j]-f0[i]|.
// One wave per row; 16 values/lane in registers; 20 rounds of
// local argmin (unrolled) + wave argmin (shfl_xor butterfly) + invalidate.
// ---------------------------------------------------------------------------
__global__ void k2_topk(const float* __restrict__ adj, const float* __restrict__ f0c,
                        int* __restrict__ nnidx) {
    int lane = threadIdx.x & 63;
    int row  = blockIdx.x * 4 + (threadIdx.x >> 6);   // b*N + i
    int b    = row >> 10;
    const float* arow = adj + (size_t)row * NN;
    const float* frow = f0c + b * NN;
    float f0i = f0c[row];
    float v[16];
#pragma unroll
    for (int t = 0; t < 16; ++t) {
        int j = lane + 64 * t;
        v[t] = arow[j] * fabsf(frow[j] - f0i);
    }
    int* out = nnidx + (size_t)row * KK;
    for (int r = 0; r < KK; ++r) {
        // local argmin over this lane's 16 survivors
        float bv = v[0];
        int   bt = 0;
#pragma unroll
        for (int t = 1; t < 16; ++t) {
            if (v[t] < bv) { bv = v[t]; bt = t; }
        }
        int bj = lane + (bt << 6);
        // wave argmin (value, then index for determinism)
        float wv = bv;
        int   wi = bj;
#pragma unroll
        for (int m = 1; m < 64; m <<= 1) {
            float ov = __shfl_xor(wv, m);
            int   oi = __shfl_xor(wi, m);
            if (ov < wv || (ov == wv && oi < wi)) { wv = ov; wi = oi; }
        }
        if (lane == 0) out[r] = wi;
        // invalidate the winner in its owner lane
        if ((wi & 63) == lane) {
            int s = wi >> 6;
#pragma unroll
            for (int t = 0; t < 16; ++t) {
                if (t == s) v[t] = FLT_MAX;
            }
        }
    }
}

// ---------------------------------------------------------------------------
// K3: per (b,n): h1[k,c] = relu((cterm[u,c] + nterm[b,idx[k],c])*s1 + sh1)
//     z2[k,c]  = h1[k,:]·w2[:,c];  out[u,c] = mean_k relu(z2*s2 + sh2)
// One wave per unit; w2 column resident in 64 VGPRs; h1 broadcast from LDS.
// ---------------------------------------------------------------------------
__global__ __launch_bounds__(64) void k3_main(
        const float* __restrict__ cterm, const float* __restrict__ nterm,
        const int* __restrict__ nnidx, const float* __restrict__ w2,
        const float* __restrict__ b2,
        const float* __restrict__ g1, const float* __restrict__ be1,
        const float* __restrict__ mu1, const float* __restrict__ v1,
        const float* __restrict__ g2, const float* __restrict__ be2,
        const float* __restrict__ mu2, const float* __restrict__ v2,
        float* __restrict__ out) {
    __shared__ int   lidx[KK];
    __shared__ float lh1[KK * CC];
    int u = blockIdx.x;          // b*N + n
    int b = u >> 10;
    int c = threadIdx.x;
    if (c < KK) lidx[c] = nnidx[(size_t)u * KK + c];
    float w[CC];
#pragma unroll
    for (int j = 0; j < CC; ++j) w[j] = w2[j * CC + c];   // column c of w2
    float ct  = cterm[(size_t)u * CC + c];                // includes b1
    float s1  = g1[c] * rsqrtf(v1[c] + EPSL);
    float sh1 = be1[c] - mu1[c] * s1;
    float s2  = g2[c] * rsqrtf(v2[c] + EPSL);
    float sh2 = (b2[c] - mu2[c]) * s2 + be2[c];           // b2 folded in
    __syncthreads();
#pragma unroll
    for (int kk = 0; kk < KK; ++kk) {
        int j = lidx[kk];
        float nt = nterm[((size_t)b * NN + j) * CC + c];
        lh1[kk * CC + c] = fmaxf((ct + nt) * s1 + sh1, 0.f);
    }
    __syncthreads();
    float osum = 0.f;
    for (int kk = 0; kk < KK; ++kk) {
        float acc = 0.f;
#pragma unroll
        for (int j = 0; j < CC; ++j) {
            acc = fmaf(lh1[kk * CC + j], w[j], acc);
        }
        osum += fmaxf(acc * s2 + sh2, 0.f);
    }
    out[(size_t)u * CC + c] = osum * (1.f / (float)KK);
}

// ---------------------------------------------------------------------------
extern "C" void kernel_launch(void* const* d_in, const int* in_sizes, int n_in,
                              void* d_out, int out_size, void* d_ws, size_t ws_size,
                              hipStream_t stream) {
    const float* feats = (const float*)d_in[0];
    const float* adj   = (const float*)d_in[1];
    const float* w1    = (const float*)d_in[2];
    const float* b1    = (const float*)d_in[3];
    const float* g1    = (const float*)d_in[4];
    const float* be1   = (const float*)d_in[5];
    const float* mu1   = (const float*)d_in[6];
    const float* v1    = (const float*)d_in[7];
    const float* w2    = (const float*)d_in[8];
    const float* b2    = (const float*)d_in[9];
    const float* g2    = (const float*)d_in[10];
    const float* be2   = (const float*)d_in[11];
    const float* mu2   = (const float*)d_in[12];
    const float* v2    = (const float*)d_in[13];
    float* out = (float*)d_out;

    char* ws = (char*)d_ws;
    float* cterm = (float*)(ws);                                  // 4 MB
    float* nterm = (float*)(ws + 4u * 1024 * 1024);               // 4 MB
    float* f0c   = (float*)(ws + 8u * 1024 * 1024);               // 64 KB
    int*   nnidx = (int*)  (ws + 8u * 1024 * 1024 + 64u * 1024);  // 1.25 MB

    // K1: 16384 units * 64 channels / 256 threads
    k1_pre<<<4096, 256, 0, stream>>>(feats, w1, b1, cterm, nterm, f0c);
    // K2: 16384 rows, 4 rows (waves) per 256-thread block
    k2_topk<<<4096, 256, 0, stream>>>(adj, f0c, nnidx);
    // K3: one 64-thread block per (b,n)
    k3_main<<<16384, 64, 0, stream>>>(cterm, nterm, nnidx, w2, b2,
                                      g1, be1, mu1, v1, g2, be2, mu2, v2, out);
}

// Round 2
// 192.664 us; speedup vs baseline: 1.2619x; 1.2619x over previous
//
#include <hip/hip_runtime.h>
#include <float.h>
#include <math.h>

#define NN 1024
#define DD 64
#define CC 64
#define KK 20
#define EPSL 1e-3f

typedef __attribute__((ext_vector_type(8))) short short8;   // 8 bf16
typedef __attribute__((ext_vector_type(4))) float f32x4;    // MFMA acc

__device__ __forceinline__ unsigned short f2bf(float f) {
    unsigned u = __float_as_uint(f);
    return (unsigned short)((u + 0x7fffu + ((u >> 16) & 1u)) >> 16);
}

// ---------------------------------------------------------------------------
// K1: cterm[u,c] = feats[u,:]·(W1a-W1b)[:,c] + b1[c];  nterm[u,c] = feats[u,:]·W1b[:,c]
// ---------------------------------------------------------------------------
__global__ __launch_bounds__(256) void k1_pre(
        const float* __restrict__ feats, const float* __restrict__ w1,
        const float* __restrict__ b1, float* __restrict__ cterm,
        float* __restrict__ nterm, float* __restrict__ f0c) {
    int g = blockIdx.x * blockDim.x + threadIdx.x;
    int u = g >> 6;
    int c = g & 63;
    const float* f = feats + (size_t)u * DD;
    float ca = 0.f, nb = 0.f;
#pragma unroll
    for (int d = 0; d < DD; ++d) {
        float fd = f[d];
        ca = fmaf(fd, w1[d * CC + c], ca);
        nb = fmaf(fd, w1[(d + DD) * CC + c], nb);
    }
    cterm[g] = ca - nb + b1[c];
    nterm[g] = nb;
    if (c == 0) f0c[u] = f[0];
}

// ---------------------------------------------------------------------------
// K2: exact top-20-smallest of a[j] = adj[row,j]*|f0[j]-f0[i]| per row.
// Threshold T = 20th smallest of the 64 per-lane minima (guarantees
// count(v<=T) >= 20); compact candidates; 64-lane bitonic sort on
// (value,index) u64 keys (index tiebreak == top_k tie rule). Wave-uniform
// fallback to 20-round argmin when count > 64 (rare, exact).
// Slot t=(tv,q) <-> j = 256*tv + 4*lane + q  (float4 loads).
// ---------------------------------------------------------------------------
__global__ __launch_bounds__(256) void k2_topk(const float* __restrict__ adj,
                                               const float* __restrict__ f0c,
                                               int* __restrict__ nnidx) {
    __shared__ unsigned long long keybuf[4][64];
    int lane = threadIdx.x & 63;
    int w    = threadIdx.x >> 6;
    int row  = blockIdx.x * 4 + w;
    int b    = row >> 10;
    const float4* arow = (const float4*)(adj + (size_t)row * NN);
    const float4* frow = (const float4*)(f0c + (size_t)b * NN);
    float f0i = f0c[row];
    unsigned vu[16];
#pragma unroll
    for (int tv = 0; tv < 4; ++tv) {
        float4 av = arow[64 * tv + lane];
        float4 fv = frow[64 * tv + lane];
        vu[tv * 4 + 0] = __float_as_uint(av.x * fabsf(fv.x - f0i));
        vu[tv * 4 + 1] = __float_as_uint(av.y * fabsf(fv.y - f0i));
        vu[tv * 4 + 2] = __float_as_uint(av.z * fabsf(fv.z - f0i));
        vu[tv * 4 + 3] = __float_as_uint(av.w * fabsf(fv.w - f0i));
    }
    // per-lane min (uint compare == float compare for nonneg)
    unsigned x = vu[0];
#pragma unroll
    for (int t = 1; t < 16; ++t) x = (vu[t] < x) ? vu[t] : x;
    // bitonic sort the 64 lane-minima ascending (values only)
#pragma unroll
    for (int k = 2; k <= 64; k <<= 1) {
#pragma unroll
        for (int j = k >> 1; j > 0; j >>= 1) {
            unsigned o = __shfl_xor(x, j);
            bool keepmin = (((lane & j) == 0) == ((lane & k) == 0));
            unsigned mn = (o < x) ? o : x;
            unsigned mx = (o < x) ? x : o;
            x = keepmin ? mn : mx;
        }
    }
    unsigned T = __shfl(x, 19);
    int cnt = 0;
#pragma unroll
    for (int t = 0; t < 16; ++t) cnt += (vu[t] <= T) ? 1 : 0;
    int inc = cnt;
#pragma unroll
    for (int off = 1; off < 64; off <<= 1) {
        int o = __shfl_up(inc, off);
        if (lane >= off) inc += o;
    }
    int total = __shfl(inc, 63);
    int* outp = nnidx + (size_t)row * KK;

    if (total <= 64) {
        int pos = inc - cnt;
#pragma unroll
        for (int t = 0; t < 16; ++t) {
            if (vu[t] <= T) {
                int j = 256 * (t >> 2) + 4 * lane + (t & 3);
                keybuf[w][pos] = ((unsigned long long)vu[t] << 32) | (unsigned)j;
                pos++;
            }
        }
        unsigned long long key = (lane < total) ? keybuf[w][lane] : ~0ull;
#pragma unroll
        for (int k = 2; k <= 64; k <<= 1) {
#pragma unroll
            for (int j = k >> 1; j > 0; j >>= 1) {
                unsigned long long o = __shfl_xor(key, j);
                bool keepmin = (((lane & j) == 0) == ((lane & k) == 0));
                bool less = (o < key);
                if (less == keepmin) key = o;
            }
        }
        if (lane < KK) outp[lane] = (int)(unsigned)key;
    } else {
        // exact fallback: 20 rounds of wave argmin with index tiebreak
        for (int r = 0; r < KK; ++r) {
            unsigned bv = vu[0];
            int bt = 0;
#pragma unroll
            for (int t = 1; t < 16; ++t) {
                if (vu[t] < bv) { bv = vu[t]; bt = t; }
            }
            int bj = 256 * (bt >> 2) + 4 * lane + (bt & 3);
            unsigned wv = bv;
            int wi = bj;
#pragma unroll
            for (int m = 1; m < 64; m <<= 1) {
                unsigned ov = __shfl_xor(wv, m);
                int oi = __shfl_xor(wi, m);
                if (ov < wv || (ov == wv && oi < wi)) { wv = ov; wi = oi; }
            }
            if (lane == 0) outp[r] = wi;
            if (((wi >> 2) & 63) == lane) {
                int s = ((wi >> 8) << 2) | (wi & 3);
#pragma unroll
                for (int t = 0; t < 16; ++t) {
                    if (t == s) vu[t] = 0xFFFFFFFFu;
                }
            }
        }
    }
}

// ---------------------------------------------------------------------------
// K3: MFMA layer-2. One wave = 4 units (M = 4*20 = 80 = 5 M-tiles), N=64, K=64.
// h1 built in wave-private LDS (bf16, row stride 72 bf16 = 144 B -> 2-way bank
// aliasing on ds_read_b128 A-frags = free). B (w2) resident in 16 VGPRs.
// Epilogue: bn2+relu per C reg; C-quads are unit-pure (20|40|60 are mult of 4)
// -> quad partial sums -> ds_add_f32 into per-wave acc -> k-mean -> store.
// No __syncthreads needed: all LDS is wave-private.
// ---------------------------------------------------------------------------
__global__ __launch_bounds__(256, 3) void k3_mfma(
        const float* __restrict__ cterm, const float* __restrict__ nterm,
        const int* __restrict__ nnidx, const float* __restrict__ w2,
        const float* __restrict__ b2,
        const float* __restrict__ g1, const float* __restrict__ be1,
        const float* __restrict__ mu1, const float* __restrict__ v1,
        const float* __restrict__ g2, const float* __restrict__ be2,
        const float* __restrict__ mu2, const float* __restrict__ v2,
        float* __restrict__ out) {
    __shared__ __align__(16) char lds[4 * 12544];
    int lane = threadIdx.x & 63;
    int w    = threadIdx.x >> 6;
    char* wbase = lds + w * 12544;
    unsigned short* lh = (unsigned short*)wbase;   // 80 x 72 bf16 (144 B rows)
    float* accb = (float*)(wbase + 11520);         // 4 units x 64 ch
    int u0  = blockIdx.x * 16 + w * 4;
    int b   = u0 >> 10;
    int col = lane & 15, quad = lane >> 4;

    // zero the per-wave accumulation buffer (ws is poisoned 0xAA)
    accb[lane] = 0.f; accb[64 + lane] = 0.f; accb[128 + lane] = 0.f; accb[192 + lane] = 0.f;

    // bn1 per channel c = lane
    float s1  = g1[lane] * rsqrtf(v1[lane] + EPSL);
    float sh1 = be1[lane] - mu1[lane] * s1;
    float ctv[4];
#pragma unroll
    for (int g = 0; g < 4; ++g) ctv[g] = cterm[(size_t)(u0 + g) * CC + lane];

    // bn2 per this lane's 4 epilogue channels (c = nt*16 + col)
    float s2v[4], sh2v[4];
#pragma unroll
    for (int nt = 0; nt < 4; ++nt) {
        int c = nt * 16 + col;
        float s2 = g2[c] * rsqrtf(v2[c] + EPSL);
        s2v[nt]  = s2;
        sh2v[nt] = (b2[c] - mu2[c]) * s2 + be2[c];
    }

    // B fragments: B[k = ks*32 + quad*8 + i][n = nt*16 + col]
    short8 bfr[4][2];
#pragma unroll
    for (int nt = 0; nt < 4; ++nt)
#pragma unroll
        for (int ks = 0; ks < 2; ++ks)
#pragma unroll
            for (int i = 0; i < 8; ++i) {
                int k = ks * 32 + quad * 8 + i;
                int c = nt * 16 + col;
                bfr[nt][ks][i] = (short)f2bf(w2[k * CC + c]);
            }

    // neighbor indices for this wave's 4 units (80 ints, held across lanes)
    const int* ib = nnidx + (size_t)u0 * KK;
    int i0 = ib[lane];
    int i1 = (lane < 16) ? ib[64 + lane] : 0;

    // build h1 in LDS: row t = g*20+kk, channel c = lane
#pragma unroll
    for (int g = 0; g < 4; ++g) {
#pragma unroll 10
        for (int kk = 0; kk < KK; ++kk) {
            int t = g * 20 + kk;
            int src = (t < 64) ? i0 : i1;
            int jr = __shfl(src, t & 63);
            float nv = nterm[((size_t)b * NN + jr) * CC + lane];
            float h = fmaxf((ctv[g] + nv) * s1 + sh1, 0.f);
            lh[t * 72 + lane] = f2bf(h);
        }
    }

    // MFMA: 5 M-tiles x 4 N-tiles x 2 K-steps
    f32x4 acc[5][4];
#pragma unroll
    for (int mt = 0; mt < 5; ++mt)
#pragma unroll
        for (int nt = 0; nt < 4; ++nt)
            acc[mt][nt] = (f32x4)(0.f);
#pragma unroll
    for (int ks = 0; ks < 2; ++ks)
#pragma unroll
        for (int mt = 0; mt < 5; ++mt) {
            short8 a = *(const short8*)(wbase + (mt * 16 + col) * 144 + ks * 64 + quad * 16);
#pragma unroll
            for (int nt = 0; nt < 4; ++nt)
                acc[mt][nt] = __builtin_amdgcn_mfma_f32_16x16x32_bf16(a, bfr[nt][ks], acc[mt][nt], 0, 0, 0);
        }

    // epilogue: bn2 + relu, quad partial k-sums, LDS accumulate
#pragma unroll
    for (int mt = 0; mt < 5; ++mt) {
        int mb = mt * 16 + quad * 4;   // first of this lane's 4 C-rows; unit-pure
        int g  = mb / 20;
#pragma unroll
        for (int nt = 0; nt < 4; ++nt) {
            float s2c = s2v[nt], sh2c = sh2v[nt];
            float s = 0.f;
#pragma unroll
            for (int r = 0; r < 4; ++r)
                s += fmaxf(acc[mt][nt][r] * s2c + sh2c, 0.f);
            atomicAdd(&accb[g * 64 + nt * 16 + col], s);
        }
    }

    // k-mean (x 1/20) and store
#pragma unroll
    for (int g = 0; g < 4; ++g)
        out[(size_t)(u0 + g) * CC + lane] = accb[g * 64 + lane] * 0.05f;
}

// ---------------------------------------------------------------------------
extern "C" void kernel_launch(void* const* d_in, const int* in_sizes, int n_in,
                              void* d_out, int out_size, void* d_ws, size_t ws_size,
                              hipStream_t stream) {
    const float* feats = (const float*)d_in[0];
    const float* adj   = (const float*)d_in[1];
    const float* w1    = (const float*)d_in[2];
    const float* b1    = (const float*)d_in[3];
    const float* g1    = (const float*)d_in[4];
    const float* be1   = (const float*)d_in[5];
    const float* mu1   = (const float*)d_in[6];
    const float* v1    = (const float*)d_in[7];
    const float* w2    = (const float*)d_in[8];
    const float* b2    = (const float*)d_in[9];
    const float* g2    = (const float*)d_in[10];
    const float* be2   = (const float*)d_in[11];
    const float* mu2   = (const float*)d_in[12];
    const float* v2    = (const float*)d_in[13];
    float* out = (float*)d_out;

    char* ws = (char*)d_ws;
    float* cterm = (float*)(ws);                                  // 4 MB
    float* nterm = (float*)(ws + 4u * 1024 * 1024);               // 4 MB
    float* f0c   = (float*)(ws + 8u * 1024 * 1024);               // 64 KB
    int*   nnidx = (int*)  (ws + 8u * 1024 * 1024 + 64u * 1024);  // 1.25 MB

    k1_pre<<<4096, 256, 0, stream>>>(feats, w1, b1, cterm, nterm, f0c);
    k2_topk<<<4096, 256, 0, stream>>>(adj, f0c, nnidx);
    k3_mfma<<<1024, 256, 0, stream>>>(cterm, nterm, nnidx, w2, b2,
                                      g1, be1, mu1, v1, g2, be2, mu2, v2, out);
}

// Round 3
// 152.829 us; speedup vs baseline: 1.5909x; 1.2607x over previous
//
#include <hip/hip_runtime.h>
#include <float.h>
#include <math.h>

#define NN 1024
#define DD 64
#define CC 64
#define KK 20
#define EPSL 1e-3f

typedef __attribute__((ext_vector_type(8))) short short8;   // 8 bf16
typedef __attribute__((ext_vector_type(4))) float f32x4;    // MFMA acc

__device__ __forceinline__ unsigned short f2bf(float f) {
    unsigned u = __float_as_uint(f);
    return (unsigned short)((u + 0x7fffu + ((u >> 16) & 1u)) >> 16);
}
__device__ __forceinline__ float bf2f(unsigned short h) {
    return __uint_as_float((unsigned)h << 16);
}

// ---------------------------------------------------------------------------
// K0: prep. b1t[n][k] (bf16, 128x64, n-major = transposed, BN1-prescaled):
//   n<64 : s1[n]*(W1a-W1b)[k][n]   (cterm weights)
//   n>=64: s1[n-64]*W1b[k][n-64]   (nterm weights)
// w2t[n][k] = bf16(w2[k][n]); bb[c] = b1*s1 + be1 - mu1*s1; f0c[u] = feats[u][0]
// ---------------------------------------------------------------------------
__global__ __launch_bounds__(256) void k0_prep(
        const float* __restrict__ w1, const float* __restrict__ w2,
        const float* __restrict__ feats, const float* __restrict__ b1,
        const float* __restrict__ g1, const float* __restrict__ be1,
        const float* __restrict__ mu1, const float* __restrict__ v1,
        unsigned short* __restrict__ b1t, unsigned short* __restrict__ w2t,
        float* __restrict__ bb, float* __restrict__ f0c) {
    int t = blockIdx.x * 256 + threadIdx.x;
    if (t < 8192) {
        int n = t >> 6, k = t & 63;
        float val;
        if (n < 64) {
            float s = g1[n] * rsqrtf(v1[n] + EPSL);
            val = (w1[k * CC + n] - w1[(k + DD) * CC + n]) * s;
        } else {
            int c = n - 64;
            float s = g1[c] * rsqrtf(v1[c] + EPSL);
            val = w1[(k + DD) * CC + c] * s;
        }
        b1t[t] = f2bf(val);
    } else if (t < 12288) {
        int i = t - 8192;
        int n = i >> 6, k = i & 63;
        w2t[i] = f2bf(w2[k * CC + n]);
    } else if (t < 12352) {
        int c = t - 12288;
        float s = g1[c] * rsqrtf(v1[c] + EPSL);
        bb[c] = b1[c] * s + be1[c] - mu1[c] * s;
    } else if (t < 28736) {
        int u = t - 12352;
        f0c[u] = feats[(size_t)u * DD];
    }
}

// ---------------------------------------------------------------------------
// K1: MFMA GEMM  [16384 x 64] @ [64 x 128] -> cterm2 | nterm2 (f32, bn1-folded).
// A = feats in split bf16 (hi + lo) for ~f32 accuracy. Block = 4 waves sharing
// M=64 rows; wave w takes N columns [32w, 32w+32). 32 MFMAs/wave.
// ---------------------------------------------------------------------------
__global__ __launch_bounds__(256) void k1_mfma(
        const float* __restrict__ feats, const unsigned short* __restrict__ b1t,
        const float* __restrict__ bb,
        float* __restrict__ cterm, float* __restrict__ nterm) {
    int lane = threadIdx.x & 63, w = threadIdx.x >> 6;
    int col = lane & 15, quad = lane >> 4;
    int m0 = blockIdx.x * 64;

    short8 bfr[2][2];
#pragma unroll
    for (int nt = 0; nt < 2; ++nt)
#pragma unroll
        for (int ks = 0; ks < 2; ++ks)
            bfr[nt][ks] = *(const short8*)(b1t + (w * 32 + nt * 16 + col) * 64 + ks * 32 + quad * 8);

    float bbv[2] = {0.f, 0.f};
    if (w < 2) {
        bbv[0] = bb[w * 32 + col];
        bbv[1] = bb[w * 32 + 16 + col];
    }

    f32x4 acc[4][2];
#pragma unroll
    for (int mt = 0; mt < 4; ++mt)
#pragma unroll
        for (int nt = 0; nt < 2; ++nt) acc[mt][nt] = (f32x4)(0.f);

#pragma unroll
    for (int mt = 0; mt < 4; ++mt) {
        const float* fr = feats + (size_t)(m0 + mt * 16 + col) * DD;
#pragma unroll
        for (int ks = 0; ks < 2; ++ks) {
            float4 p0 = *(const float4*)(fr + ks * 32 + quad * 8);
            float4 p1 = *(const float4*)(fr + ks * 32 + quad * 8 + 4);
            float f[8] = {p0.x, p0.y, p0.z, p0.w, p1.x, p1.y, p1.z, p1.w};
            short8 ah, al;
#pragma unroll
            for (int i = 0; i < 8; ++i) {
                unsigned short h = f2bf(f[i]);
                ah[i] = (short)h;
                al[i] = (short)f2bf(f[i] - bf2f(h));
            }
#pragma unroll
            for (int nt = 0; nt < 2; ++nt) {
                acc[mt][nt] = __builtin_amdgcn_mfma_f32_16x16x32_bf16(ah, bfr[nt][ks], acc[mt][nt], 0, 0, 0);
                acc[mt][nt] = __builtin_amdgcn_mfma_f32_16x16x32_bf16(al, bfr[nt][ks], acc[mt][nt], 0, 0, 0);
            }
        }
    }

#pragma unroll
    for (int mt = 0; mt < 4; ++mt)
#pragma unroll
        for (int nt = 0; nt < 2; ++nt) {
            int n = w * 32 + nt * 16 + col;
#pragma unroll
            for (int r = 0; r < 4; ++r) {
                int m = m0 + mt * 16 + quad * 4 + r;
                float v = acc[mt][nt][r];
                if (w < 2) cterm[(size_t)m * CC + n] = v + bbv[nt];
                else       nterm[(size_t)m * CC + (n - 64)] = v;
            }
        }
}

// ---------------------------------------------------------------------------
// K2: exact bottom-20 set of a[j] = adj[row,j]*|f0[j]-f0[i]| per row.
// T = 20th smallest of 64 lane-minima (u32 bitonic) -> candidates <= 64 ->
// compact (val<<32|idx) to LDS -> u32 bitonic on candidate VALUES -> exact
// 20th value T* -> ballot/popcount emission. Order-free (mean over k).
// Wave-uniform exact fallback if candidates > 64.
// ---------------------------------------------------------------------------
__global__ __launch_bounds__(256) void k2_topk(const float* __restrict__ adj,
                                               const float* __restrict__ f0c,
                                               int* __restrict__ nnidx) {
    __shared__ unsigned long long keybuf[4][64];
    int lane = threadIdx.x & 63;
    int w    = threadIdx.x >> 6;
    int row  = blockIdx.x * 4 + w;
    int b    = row >> 10;
    const float4* arow = (const float4*)(adj + (size_t)row * NN);
    const float4* frow = (const float4*)(f0c + (size_t)b * NN);
    float f0i = f0c[row];
    unsigned vu[16];
#pragma unroll
    for (int tv = 0; tv < 4; ++tv) {
        float4 av = arow[64 * tv + lane];
        float4 fv = frow[64 * tv + lane];
        vu[tv * 4 + 0] = __float_as_uint(av.x * fabsf(fv.x - f0i));
        vu[tv * 4 + 1] = __float_as_uint(av.y * fabsf(fv.y - f0i));
        vu[tv * 4 + 2] = __float_as_uint(av.z * fabsf(fv.z - f0i));
        vu[tv * 4 + 3] = __float_as_uint(av.w * fabsf(fv.w - f0i));
    }
    unsigned x = vu[0];
#pragma unroll
    for (int t = 1; t < 16; ++t) x = (vu[t] < x) ? vu[t] : x;
    // bitonic ascending sort of the 64 lane-minima (values only, u32)
#pragma unroll
    for (int k = 2; k <= 64; k <<= 1) {
#pragma unroll
        for (int j = k >> 1; j > 0; j >>= 1) {
            unsigned o = __shfl_xor(x, j);
            bool keepmin = (((lane & j) == 0) == ((lane & k) == 0));
            unsigned mn = (o < x) ? o : x;
            unsigned mx = (o < x) ? x : o;
            x = keepmin ? mn : mx;
        }
    }
    unsigned T = __shfl(x, 19);
    int cnt = 0;
#pragma unroll
    for (int t = 0; t < 16; ++t) cnt += (vu[t] <= T) ? 1 : 0;
    int inc = cnt;
#pragma unroll
    for (int off = 1; off < 64; off <<= 1) {
        int o = __shfl_up(inc, off);
        if (lane >= off) inc += o;
    }
    int total = __shfl(inc, 63);
    int* outp = nnidx + (size_t)row * KK;

    if (total <= 64) {
        int pos = inc - cnt;
#pragma unroll
        for (int t = 0; t < 16; ++t) {
            if (vu[t] <= T) {
                int j = 256 * (t >> 2) + 4 * lane + (t & 3);
                keybuf[w][pos] = ((unsigned long long)vu[t] << 32) | (unsigned)j;
                pos++;
            }
        }
        unsigned long long key = (lane < total) ? keybuf[w][lane] : ~0ull;
        unsigned y = (unsigned)(key >> 32);
        // bitonic sort candidate values (u32) to find exact 20th smallest
#pragma unroll
        for (int k = 2; k <= 64; k <<= 1) {
#pragma unroll
            for (int j = k >> 1; j > 0; j >>= 1) {
                unsigned o = __shfl_xor(y, j);
                bool keepmin = (((lane & j) == 0) == ((lane & k) == 0));
                unsigned mn = (o < y) ? o : y;
                unsigned mx = (o < y) ? y : o;
                y = keepmin ? mn : mx;
            }
        }
        unsigned Tstar = __shfl(y, 19);
        bool fl = (lane < total) && ((unsigned)(key >> 32) <= Tstar);
        unsigned long long msk = __ballot(fl);
        int p = __popcll(msk & ((1ull << lane) - 1ull));
        if (fl && p < KK) outp[p] = (int)(unsigned)key;
    } else {
        for (int r = 0; r < KK; ++r) {
            unsigned bv = vu[0];
            int bt = 0;
#pragma unroll
            for (int t = 1; t < 16; ++t) {
                if (vu[t] < bv) { bv = vu[t]; bt = t; }
            }
            int bj = 256 * (bt >> 2) + 4 * lane + (bt & 3);
            unsigned wv = bv;
            int wi = bj;
#pragma unroll
            for (int m = 1; m < 64; m <<= 1) {
                unsigned ov = __shfl_xor(wv, m);
                int oi = __shfl_xor(wi, m);
                if (ov < wv || (ov == wv && oi < wi)) { wv = ov; wi = oi; }
            }
            if (lane == 0) outp[r] = wi;
            if (((wi >> 2) & 63) == lane) {
                int s = ((wi >> 8) << 2) | (wi & 3);
#pragma unroll
                for (int t = 0; t < 16; ++t) {
                    if (t == s) vu[t] = 0xFFFFFFFFu;
                }
            }
        }
    }
}

// ---------------------------------------------------------------------------
// K3: LDS-free MFMA layer-2. One wave = 4 units (M=80), N=64, K=64.
// Each lane builds its OWN A-fragment rows directly from global:
//   A[m=mt*16+col][k=ks*32+quad*8+i] = relu(cterm2 + nterm2)  (float4 loads).
// 40 MFMAs/wave. Epilogue: bn2+relu per C reg, static routing of quad-sums
// to 4 unit accumulators, shfl_xor(16,32) cross-quad reduce, quad q stores
// unit q. Zero LDS.
// ---------------------------------------------------------------------------
__global__ __launch_bounds__(256, 3) void k3_mfma(
        const float* __restrict__ cterm, const float* __restrict__ nterm,
        const int* __restrict__ nnidx, const unsigned short* __restrict__ w2t,
        const float* __restrict__ b2,
        const float* __restrict__ g2, const float* __restrict__ be2,
        const float* __restrict__ mu2, const float* __restrict__ v2,
        float* __restrict__ out) {
    int lane = threadIdx.x & 63, w = threadIdx.x >> 6;
    int col = lane & 15, quad = lane >> 4;
    int wid = blockIdx.x * 4 + w;
    int u0 = wid * 4;
    int b  = u0 >> 10;

    short8 bfr[4][2];
#pragma unroll
    for (int nt = 0; nt < 4; ++nt)
#pragma unroll
        for (int ks = 0; ks < 2; ++ks)
            bfr[nt][ks] = *(const short8*)(w2t + (nt * 16 + col) * 64 + ks * 32 + quad * 8);

    float s2v[4], sh2v[4];
#pragma unroll
    for (int nt = 0; nt < 4; ++nt) {
        int c = nt * 16 + col;
        float s2 = g2[c] * rsqrtf(v2[c] + EPSL);
        s2v[nt]  = s2;
        sh2v[nt] = (b2[c] - mu2[c]) * s2 + be2[c];
    }

    f32x4 acc[5][4];
#pragma unroll
    for (int mt = 0; mt < 5; ++mt)
#pragma unroll
        for (int nt = 0; nt < 4; ++nt) acc[mt][nt] = (f32x4)(0.f);

    const int* ibase = nnidx + (size_t)u0 * KK;
#pragma unroll
    for (int mt = 0; mt < 5; ++mt) {
        int row = mt * 16 + col;             // 0..79
        int g   = (row * 205) >> 12;         // row / 20
        int j   = ibase[row];
        const float* np = nterm + (size_t)(b * NN + j) * CC;
        const float* cp = cterm + (size_t)(u0 + g) * CC;
        short8 afr[2];
#pragma unroll
        for (int ks = 0; ks < 2; ++ks) {
            int ch = ks * 32 + quad * 8;
            float4 n0 = *(const float4*)(np + ch);
            float4 n1 = *(const float4*)(np + ch + 4);
            float4 c0 = *(const float4*)(cp + ch);
            float4 c1 = *(const float4*)(cp + ch + 4);
            float h[8];
            h[0] = fmaxf(c0.x + n0.x, 0.f); h[1] = fmaxf(c0.y + n0.y, 0.f);
            h[2] = fmaxf(c0.z + n0.z, 0.f); h[3] = fmaxf(c0.w + n0.w, 0.f);
            h[4] = fmaxf(c1.x + n1.x, 0.f); h[5] = fmaxf(c1.y + n1.y, 0.f);
            h[6] = fmaxf(c1.z + n1.z, 0.f); h[7] = fmaxf(c1.w + n1.w, 0.f);
#pragma unroll
            for (int i = 0; i < 8; ++i) afr[ks][i] = (short)f2bf(h[i]);
        }
#pragma unroll
        for (int ks = 0; ks < 2; ++ks)
#pragma unroll
            for (int nt = 0; nt < 4; ++nt)
                acc[mt][nt] = __builtin_amdgcn_mfma_f32_16x16x32_bf16(afr[ks], bfr[nt][ks], acc[mt][nt], 0, 0, 0);
    }

    // epilogue: bn2+relu, static unit routing, cross-quad butterfly
    float us0[4] = {0,0,0,0}, us1[4] = {0,0,0,0}, us2[4] = {0,0,0,0}, us3[4] = {0,0,0,0};
#pragma unroll
    for (int mt = 0; mt < 5; ++mt)
#pragma unroll
        for (int nt = 0; nt < 4; ++nt) {
            float qs = 0.f;
#pragma unroll
            for (int r = 0; r < 4; ++r)
                qs += fmaxf(acc[mt][nt][r] * s2v[nt] + sh2v[nt], 0.f);
            if (mt == 0) us0[nt] += qs;
            else if (mt == 4) us3[nt] += qs;
            else if (mt == 1) { float t = (quad >= 1) ? qs : 0.f; us1[nt] += t; us0[nt] += qs - t; }
            else if (mt == 2) { float t = (quad >= 2) ? qs : 0.f; us2[nt] += t; us1[nt] += qs - t; }
            else              { float t = (quad >= 3) ? qs : 0.f; us3[nt] += t; us2[nt] += qs - t; }
        }
#pragma unroll
    for (int nt = 0; nt < 4; ++nt) {
        us0[nt] += __shfl_xor(us0[nt], 16); us0[nt] += __shfl_xor(us0[nt], 32);
        us1[nt] += __shfl_xor(us1[nt], 16); us1[nt] += __shfl_xor(us1[nt], 32);
        us2[nt] += __shfl_xor(us2[nt], 16); us2[nt] += __shfl_xor(us2[nt], 32);
        us3[nt] += __shfl_xor(us3[nt], 16); us3[nt] += __shfl_xor(us3[nt], 32);
    }
#pragma unroll
    for (int nt = 0; nt < 4; ++nt) {
        float v = (quad == 0) ? us0[nt] : (quad == 1) ? us1[nt] : (quad == 2) ? us2[nt] : us3[nt];
        out[(size_t)(u0 + quad) * CC + nt * 16 + col] = v * 0.05f;
    }
}

// ---------------------------------------------------------------------------
extern "C" void kernel_launch(void* const* d_in, const int* in_sizes, int n_in,
                              void* d_out, int out_size, void* d_ws, size_t ws_size,
                              hipStream_t stream) {
    const float* feats = (const float*)d_in[0];
    const float* adj   = (const float*)d_in[1];
    const float* w1    = (const float*)d_in[2];
    const float* b1    = (const float*)d_in[3];
    const float* g1    = (const float*)d_in[4];
    const float* be1   = (const float*)d_in[5];
    const float* mu1   = (const float*)d_in[6];
    const float* v1    = (const float*)d_in[7];
    const float* w2    = (const float*)d_in[8];
    const float* b2    = (const float*)d_in[9];
    const float* g2    = (const float*)d_in[10];
    const float* be2   = (const float*)d_in[11];
    const float* mu2   = (const float*)d_in[12];
    const float* v2    = (const float*)d_in[13];
    float* out = (float*)d_out;

    char* ws = (char*)d_ws;
    float*          cterm = (float*)(ws);                                   // 4 MB
    float*          nterm = (float*)(ws + 4u * 1024 * 1024);                // 4 MB
    float*          f0c   = (float*)(ws + 8u * 1024 * 1024);                // 64 KB
    int*            nnidx = (int*)  (ws + 8u * 1024 * 1024 + 64u * 1024);   // 1.25 MB
    unsigned short* b1t   = (unsigned short*)(ws + 10u * 1024 * 1024);      // 16 KB
    unsigned short* w2t   = (unsigned short*)(ws + 10u * 1024 * 1024 + 16u * 1024); // 8 KB
    float*          bb    = (float*)(ws + 10u * 1024 * 1024 + 24u * 1024);  // 256 B

    k0_prep<<<113, 256, 0, stream>>>(w1, w2, feats, b1, g1, be1, mu1, v1,
                                     b1t, w2t, bb, f0c);
    k1_mfma<<<256, 256, 0, stream>>>(feats, b1t, bb, cterm, nterm);
    k2_topk<<<4096, 256, 0, stream>>>(adj, f0c, nnidx);
    k3_mfma<<<1024, 256, 0, stream>>>(cterm, nterm, nnidx, w2t, b2,
                                      g2, be2, mu2, v2, out);
}

// Round 4
// 148.128 us; speedup vs baseline: 1.6413x; 1.0317x over previous
//
#include <hip/hip_runtime.h>
#include <float.h>
#include <math.h>

#define NN 1024
#define DD 64
#define CC 64
#define KK 20
#define EPSL 1e-3f

typedef __attribute__((ext_vector_type(8))) short short8;   // 8 bf16
typedef __attribute__((ext_vector_type(4))) float f32x4;    // MFMA acc

__device__ __forceinline__ unsigned short f2bf(float f) {
    unsigned u = __float_as_uint(f);
    return (unsigned short)((u + 0x7fffu + ((u >> 16) & 1u)) >> 16);
}
__device__ __forceinline__ float bf2f(unsigned short h) {
    return __uint_as_float((unsigned)h << 16);
}

// ---------------------------------------------------------------------------
// K0: prep. b1t[n][k] (bf16, 128x64, n-major, BN1-prescaled):
//   n<64 : s1[n]*(W1a-W1b)[k][n]   (cterm weights)
//   n>=64: s1[n-64]*W1b[k][n-64]   (nterm weights)
// w2t[n][k] = bf16(w2[k][n]); bb[c] = b1*s1 + be1 - mu1*s1; f0c[u] = feats[u][0]
// ---------------------------------------------------------------------------
__global__ __launch_bounds__(256) void k0_prep(
        const float* __restrict__ w1, const float* __restrict__ w2,
        const float* __restrict__ feats, const float* __restrict__ b1,
        const float* __restrict__ g1, const float* __restrict__ be1,
        const float* __restrict__ mu1, const float* __restrict__ v1,
        unsigned short* __restrict__ b1t, unsigned short* __restrict__ w2t,
        float* __restrict__ bb, float* __restrict__ f0c) {
    int t = blockIdx.x * 256 + threadIdx.x;
    if (t < 8192) {
        int n = t >> 6, k = t & 63;
        float val;
        if (n < 64) {
            float s = g1[n] * rsqrtf(v1[n] + EPSL);
            val = (w1[k * CC + n] - w1[(k + DD) * CC + n]) * s;
        } else {
            int c = n - 64;
            float s = g1[c] * rsqrtf(v1[c] + EPSL);
            val = w1[(k + DD) * CC + c] * s;
        }
        b1t[t] = f2bf(val);
    } else if (t < 12288) {
        int i = t - 8192;
        int n = i >> 6, k = i & 63;
        w2t[i] = f2bf(w2[k * CC + n]);
    } else if (t < 12352) {
        int c = t - 12288;
        float s = g1[c] * rsqrtf(v1[c] + EPSL);
        bb[c] = b1[c] * s + be1[c] - mu1[c] * s;
    } else if (t < 28736) {
        int u = t - 12352;
        f0c[u] = feats[(size_t)u * DD];
    }
}

// ---------------------------------------------------------------------------
// K1: MFMA GEMM  [16384 x 64] @ [64 x 128] -> cterm | nterm (bf16, bn1-folded).
// Re-tiled for occupancy: block = M=16 rows, 4 waves x N=32 cols each ->
// 1024 blocks = 4 blocks/CU = 4 waves/SIMD (was 256 blocks = 1 wave/SIMD).
// A = feats in split bf16 (hi+lo) for ~f32 accuracy. 8 MFMAs/wave.
// ---------------------------------------------------------------------------
__global__ __launch_bounds__(256) void k1_mfma(
        const float* __restrict__ feats, const unsigned short* __restrict__ b1t,
        const float* __restrict__ bb,
        unsigned short* __restrict__ cterm, unsigned short* __restrict__ nterm) {
    int lane = threadIdx.x & 63, w = threadIdx.x >> 6;
    int col = lane & 15, quad = lane >> 4;
    int m0 = blockIdx.x * 16;
    int nb = w * 32;

    short8 bfr[2][2];
#pragma unroll
    for (int nt = 0; nt < 2; ++nt)
#pragma unroll
        for (int ks = 0; ks < 2; ++ks)
            bfr[nt][ks] = *(const short8*)(b1t + (nb + nt * 16 + col) * 64 + ks * 32 + quad * 8);

    float bbv[2] = {0.f, 0.f};
    if (w < 2) {
        bbv[0] = bb[nb + col];
        bbv[1] = bb[nb + 16 + col];
    }

    f32x4 acc[2];
    acc[0] = (f32x4)(0.f);
    acc[1] = (f32x4)(0.f);

    const float* fr = feats + (size_t)(m0 + col) * DD;
#pragma unroll
    for (int ks = 0; ks < 2; ++ks) {
        float4 p0 = *(const float4*)(fr + ks * 32 + quad * 8);
        float4 p1 = *(const float4*)(fr + ks * 32 + quad * 8 + 4);
        float f[8] = {p0.x, p0.y, p0.z, p0.w, p1.x, p1.y, p1.z, p1.w};
        short8 ah, al;
#pragma unroll
        for (int i = 0; i < 8; ++i) {
            unsigned short h = f2bf(f[i]);
            ah[i] = (short)h;
            al[i] = (short)f2bf(f[i] - bf2f(h));
        }
#pragma unroll
        for (int nt = 0; nt < 2; ++nt) {
            acc[nt] = __builtin_amdgcn_mfma_f32_16x16x32_bf16(ah, bfr[nt][ks], acc[nt], 0, 0, 0);
            acc[nt] = __builtin_amdgcn_mfma_f32_16x16x32_bf16(al, bfr[nt][ks], acc[nt], 0, 0, 0);
        }
    }

#pragma unroll
    for (int nt = 0; nt < 2; ++nt) {
        int n = nb + nt * 16 + col;
#pragma unroll
        for (int r = 0; r < 4; ++r) {
            int m = m0 + quad * 4 + r;
            unsigned short v = f2bf(acc[nt][r] + bbv[nt]);
            if (w < 2) cterm[(size_t)m * CC + n] = v;
            else       nterm[(size_t)m * CC + (n - 64)] = v;
        }
    }
}

// ---------------------------------------------------------------------------
// K2: exact bottom-20 set of a[j] = adj[row,j]*|f0[j]-f0[i]| per row.
// T = 20th smallest of 64 lane-minima (u32 bitonic) -> candidates <= 64 ->
// compact (val<<32|idx) to LDS -> u32 bitonic on candidate VALUES -> exact
// 20th value T* -> ballot/popcount emission. Order-free (mean over k).
// Wave-uniform exact fallback if candidates > 64.
// ---------------------------------------------------------------------------
__global__ __launch_bounds__(256) void k2_topk(const float* __restrict__ adj,
                                               const float* __restrict__ f0c,
                                               int* __restrict__ nnidx) {
    __shared__ unsigned long long keybuf[4][64];
    int lane = threadIdx.x & 63;
    int w    = threadIdx.x >> 6;
    int row  = blockIdx.x * 4 + w;
    int b    = row >> 10;
    const float4* arow = (const float4*)(adj + (size_t)row * NN);
    const float4* frow = (const float4*)(f0c + (size_t)b * NN);
    float f0i = f0c[row];
    unsigned vu[16];
#pragma unroll
    for (int tv = 0; tv < 4; ++tv) {
        float4 av = arow[64 * tv + lane];
        float4 fv = frow[64 * tv + lane];
        vu[tv * 4 + 0] = __float_as_uint(av.x * fabsf(fv.x - f0i));
        vu[tv * 4 + 1] = __float_as_uint(av.y * fabsf(fv.y - f0i));
        vu[tv * 4 + 2] = __float_as_uint(av.z * fabsf(fv.z - f0i));
        vu[tv * 4 + 3] = __float_as_uint(av.w * fabsf(fv.w - f0i));
    }
    unsigned x = vu[0];
#pragma unroll
    for (int t = 1; t < 16; ++t) x = (vu[t] < x) ? vu[t] : x;
#pragma unroll
    for (int k = 2; k <= 64; k <<= 1) {
#pragma unroll
        for (int j = k >> 1; j > 0; j >>= 1) {
            unsigned o = __shfl_xor(x, j);
            bool keepmin = (((lane & j) == 0) == ((lane & k) == 0));
            unsigned mn = (o < x) ? o : x;
            unsigned mx = (o < x) ? x : o;
            x = keepmin ? mn : mx;
        }
    }
    unsigned T = __shfl(x, 19);
    int cnt = 0;
#pragma unroll
    for (int t = 0; t < 16; ++t) cnt += (vu[t] <= T) ? 1 : 0;
    int inc = cnt;
#pragma unroll
    for (int off = 1; off < 64; off <<= 1) {
        int o = __shfl_up(inc, off);
        if (lane >= off) inc += o;
    }
    int total = __shfl(inc, 63);
    int* outp = nnidx + (size_t)row * KK;

    if (total <= 64) {
        int pos = inc - cnt;
#pragma unroll
        for (int t = 0; t < 16; ++t) {
            if (vu[t] <= T) {
                int j = 256 * (t >> 2) + 4 * lane + (t & 3);
                keybuf[w][pos] = ((unsigned long long)vu[t] << 32) | (unsigned)j;
                pos++;
            }
        }
        unsigned long long key = (lane < total) ? keybuf[w][lane] : ~0ull;
        unsigned y = (unsigned)(key >> 32);
#pragma unroll
        for (int k = 2; k <= 64; k <<= 1) {
#pragma unroll
            for (int j = k >> 1; j > 0; j >>= 1) {
                unsigned o = __shfl_xor(y, j);
                bool keepmin = (((lane & j) == 0) == ((lane & k) == 0));
                unsigned mn = (o < y) ? o : y;
                unsigned mx = (o < y) ? y : o;
                y = keepmin ? mn : mx;
            }
        }
        unsigned Tstar = __shfl(y, 19);
        bool fl = (lane < total) && ((unsigned)(key >> 32) <= Tstar);
        unsigned long long msk = __ballot(fl);
        int p = __popcll(msk & ((1ull << lane) - 1ull));
        if (fl && p < KK) outp[p] = (int)(unsigned)key;
    } else {
        for (int r = 0; r < KK; ++r) {
            unsigned bv = vu[0];
            int bt = 0;
#pragma unroll
            for (int t = 1; t < 16; ++t) {
                if (vu[t] < bv) { bv = vu[t]; bt = t; }
            }
            int bj = 256 * (bt >> 2) + 4 * lane + (bt & 3);
            unsigned wv = bv;
            int wi = bj;
#pragma unroll
            for (int m = 1; m < 64; m <<= 1) {
                unsigned ov = __shfl_xor(wv, m);
                int oi = __shfl_xor(wi, m);
                if (ov < wv || (ov == wv && oi < wi)) { wv = ov; wi = oi; }
            }
            if (lane == 0) outp[r] = wi;
            if (((wi >> 2) & 63) == lane) {
                int s = ((wi >> 8) << 2) | (wi & 3);
#pragma unroll
                for (int t = 0; t < 16; ++t) {
                    if (t == s) vu[t] = 0xFFFFFFFFu;
                }
            }
        }
    }
}

// ---------------------------------------------------------------------------
// K3: LDS-free MFMA layer-2. One wave = 4 units (M=80), N=64, K=64.
// cterm/nterm are bf16 now: A-frag build is 2 short8 loads per (row,ks)
// (half the gather traffic/instructions of the f32 version).
// 40 MFMAs/wave. Epilogue: bn2+relu per C reg, static routing of quad-sums
// to 4 unit accumulators, shfl_xor(16,32) cross-quad reduce. Zero LDS.
// ---------------------------------------------------------------------------
__global__ __launch_bounds__(256, 3) void k3_mfma(
        const unsigned short* __restrict__ cterm, const unsigned short* __restrict__ nterm,
        const int* __restrict__ nnidx, const unsigned short* __restrict__ w2t,
        const float* __restrict__ b2,
        const float* __restrict__ g2, const float* __restrict__ be2,
        const float* __restrict__ mu2, const float* __restrict__ v2,
        float* __restrict__ out) {
    int lane = threadIdx.x & 63, w = threadIdx.x >> 6;
    int col = lane & 15, quad = lane >> 4;
    int wid = blockIdx.x * 4 + w;
    int u0 = wid * 4;
    int b  = u0 >> 10;

    short8 bfr[4][2];
#pragma unroll
    for (int nt = 0; nt < 4; ++nt)
#pragma unroll
        for (int ks = 0; ks < 2; ++ks)
            bfr[nt][ks] = *(const short8*)(w2t + (nt * 16 + col) * 64 + ks * 32 + quad * 8);

    float s2v[4], sh2v[4];
#pragma unroll
    for (int nt = 0; nt < 4; ++nt) {
        int c = nt * 16 + col;
        float s2 = g2[c] * rsqrtf(v2[c] + EPSL);
        s2v[nt]  = s2;
        sh2v[nt] = (b2[c] - mu2[c]) * s2 + be2[c];
    }

    f32x4 acc[5][4];
#pragma unroll
    for (int mt = 0; mt < 5; ++mt)
#pragma unroll
        for (int nt = 0; nt < 4; ++nt) acc[mt][nt] = (f32x4)(0.f);

    const int* ibase = nnidx + (size_t)u0 * KK;
    int jrow[5];
#pragma unroll
    for (int mt = 0; mt < 5; ++mt) jrow[mt] = ibase[mt * 16 + col];

#pragma unroll
    for (int mt = 0; mt < 5; ++mt) {
        int row = mt * 16 + col;             // 0..79
        int g   = (row * 205) >> 12;         // row / 20
        const unsigned short* np = nterm + (size_t)(b * NN + jrow[mt]) * CC;
        const unsigned short* cp = cterm + (size_t)(u0 + g) * CC;
        short8 afr[2];
#pragma unroll
        for (int ks = 0; ks < 2; ++ks) {
            int ch = ks * 32 + quad * 8;
            short8 nv = *(const short8*)(np + ch);
            short8 cv = *(const short8*)(cp + ch);
#pragma unroll
            for (int i = 0; i < 8; ++i) {
                float h = bf2f((unsigned short)cv[i]) + bf2f((unsigned short)nv[i]);
                afr[ks][i] = (short)f2bf(fmaxf(h, 0.f));
            }
        }
#pragma unroll
        for (int ks = 0; ks < 2; ++ks)
#pragma unroll
            for (int nt = 0; nt < 4; ++nt)
                acc[mt][nt] = __builtin_amdgcn_mfma_f32_16x16x32_bf16(afr[ks], bfr[nt][ks], acc[mt][nt], 0, 0, 0);
    }

    // epilogue: bn2+relu, static unit routing, cross-quad butterfly
    float us0[4] = {0,0,0,0}, us1[4] = {0,0,0,0}, us2[4] = {0,0,0,0}, us3[4] = {0,0,0,0};
#pragma unroll
    for (int mt = 0; mt < 5; ++mt)
#pragma unroll
        for (int nt = 0; nt < 4; ++nt) {
            float qs = 0.f;
#pragma unroll
            for (int r = 0; r < 4; ++r)
                qs += fmaxf(acc[mt][nt][r] * s2v[nt] + sh2v[nt], 0.f);
            if (mt == 0) us0[nt] += qs;
            else if (mt == 4) us3[nt] += qs;
            else if (mt == 1) { float t = (quad >= 1) ? qs : 0.f; us1[nt] += t; us0[nt] += qs - t; }
            else if (mt == 2) { float t = (quad >= 2) ? qs : 0.f; us2[nt] += t; us1[nt] += qs - t; }
            else              { float t = (quad >= 3) ? qs : 0.f; us3[nt] += t; us2[nt] += qs - t; }
        }
#pragma unroll
    for (int nt = 0; nt < 4; ++nt) {
        us0[nt] += __shfl_xor(us0[nt], 16); us0[nt] += __shfl_xor(us0[nt], 32);
        us1[nt] += __shfl_xor(us1[nt], 16); us1[nt] += __shfl_xor(us1[nt], 32);
        us2[nt] += __shfl_xor(us2[nt], 16); us2[nt] += __shfl_xor(us2[nt], 32);
        us3[nt] += __shfl_xor(us3[nt], 16); us3[nt] += __shfl_xor(us3[nt], 32);
    }
#pragma unroll
    for (int nt = 0; nt < 4; ++nt) {
        float v = (quad == 0) ? us0[nt] : (quad == 1) ? us1[nt] : (quad == 2) ? us2[nt] : us3[nt];
        out[(size_t)(u0 + quad) * CC + nt * 16 + col] = v * 0.05f;
    }
}

// ---------------------------------------------------------------------------
extern "C" void kernel_launch(void* const* d_in, const int* in_sizes, int n_in,
                              void* d_out, int out_size, void* d_ws, size_t ws_size,
                              hipStream_t stream) {
    const float* feats = (const float*)d_in[0];
    const float* adj   = (const float*)d_in[1];
    const float* w1    = (const float*)d_in[2];
    const float* b1    = (const float*)d_in[3];
    const float* g1    = (const float*)d_in[4];
    const float* be1   = (const float*)d_in[5];
    const float* mu1   = (const float*)d_in[6];
    const float* v1    = (const float*)d_in[7];
    const float* w2    = (const float*)d_in[8];
    const float* b2    = (const float*)d_in[9];
    const float* g2    = (const float*)d_in[10];
    const float* be2   = (const float*)d_in[11];
    const float* mu2   = (const float*)d_in[12];
    const float* v2    = (const float*)d_in[13];
    float* out = (float*)d_out;

    char* ws = (char*)d_ws;
    unsigned short* cterm = (unsigned short*)(ws);                          // 2 MB
    unsigned short* nterm = (unsigned short*)(ws + 2u * 1024 * 1024);       // 2 MB
    float*          f0c   = (float*)(ws + 4u * 1024 * 1024);                // 64 KB
    int*            nnidx = (int*)  (ws + 4u * 1024 * 1024 + 64u * 1024);   // 1.25 MB
    unsigned short* b1t   = (unsigned short*)(ws + 6u * 1024 * 1024);       // 16 KB
    unsigned short* w2t   = (unsigned short*)(ws + 6u * 1024 * 1024 + 16u * 1024); // 8 KB
    float*          bb    = (float*)(ws + 6u * 1024 * 1024 + 24u * 1024);   // 256 B

    k0_prep<<<113, 256, 0, stream>>>(w1, w2, feats, b1, g1, be1, mu1, v1,
                                     b1t, w2t, bb, f0c);
    k1_mfma<<<1024, 256, 0, stream>>>(feats, b1t, bb, cterm, nterm);
    k2_topk<<<4096, 256, 0, stream>>>(adj, f0c, nnidx);
    k3_mfma<<<1024, 256, 0, stream>>>(cterm, nterm, nnidx, w2t, b2,
                                      g2, be2, mu2, v2, out);
}